// Round 1
// baseline (4204.565 us; speedup 1.0000x reference)
//
#include <hip/hip_runtime.h>
#include <stdint.h>

#define N_ENT 100000
#define N_USR 50000
#define NREG  2597
#define REG0  42033
#define CHAN  128
#define NEDGE 2000000
#define NNZI  1000000
#define SCAN_B 1024

// ---------------- CSR build ----------------

__global__ void k_hist(const int* __restrict__ idx, int* __restrict__ cnt, int n) {
  int i = blockIdx.x * blockDim.x + threadIdx.x;
  if (i < n) atomicAdd(&cnt[idx[i]], 1);
}

__global__ void k_scan1(const int* __restrict__ cnt, int* __restrict__ partial,
                        int* __restrict__ bsum, int n) {
  __shared__ int tmp[SCAN_B];
  int i = blockIdx.x * SCAN_B + threadIdx.x;
  int x = (i < n) ? cnt[i] : 0;
  tmp[threadIdx.x] = x;
  __syncthreads();
  for (int off = 1; off < SCAN_B; off <<= 1) {
    int y = (threadIdx.x >= off) ? tmp[threadIdx.x - off] : 0;
    __syncthreads();
    tmp[threadIdx.x] += y;
    __syncthreads();
  }
  if (i < n) partial[i] = tmp[threadIdx.x];
  if (threadIdx.x == SCAN_B - 1) bsum[blockIdx.x] = tmp[threadIdx.x];
}

__global__ void k_scan2(const int* __restrict__ bsum, int* __restrict__ boff, int nb) {
  __shared__ int tmp[SCAN_B];
  int x = (threadIdx.x < nb) ? bsum[threadIdx.x] : 0;
  tmp[threadIdx.x] = x;
  __syncthreads();
  for (int off = 1; off < SCAN_B; off <<= 1) {
    int y = (threadIdx.x >= off) ? tmp[threadIdx.x - off] : 0;
    __syncthreads();
    tmp[threadIdx.x] += y;
    __syncthreads();
  }
  if (threadIdx.x < nb) boff[threadIdx.x] = tmp[threadIdx.x] - x;  // exclusive
}

// cnt_cursor holds counts on entry, exclusive write-cursors on exit
__global__ void k_scan3(int* cnt_cursor, const int* __restrict__ partial,
                        const int* __restrict__ boff, int* __restrict__ rowptr, int n) {
  int i = blockIdx.x * blockDim.x + threadIdx.x;
  if (i < n) {
    int cv = cnt_cursor[i];
    int incl = partial[i] + boff[i / SCAN_B];
    rowptr[i + 1] = incl;
    cnt_cursor[i] = incl - cv;
    if (i == 0) rowptr[0] = 0;
  }
}

__global__ void k_scatter_e(const int* __restrict__ head, const int* __restrict__ tail,
                            const int* __restrict__ type, int* __restrict__ cursor,
                            int* __restrict__ pk, int n) {
  int i = blockIdx.x * blockDim.x + threadIdx.x;
  if (i < n) {
    int pos = atomicAdd(&cursor[head[i]], 1);
    pk[pos] = ((type[i] - 1) << 17) | tail[i];   // rel 5b | tail 17b
  }
}

__global__ void k_scatter_u(const int* __restrict__ rows, const int* __restrict__ cols,
                            const float* __restrict__ vals, int* __restrict__ cursor,
                            int2* __restrict__ pk, int n) {
  int i = blockIdx.x * blockDim.x + threadIdx.x;
  if (i < n) {
    int pos = atomicAdd(&cursor[rows[i]], 1);
    pk[pos] = make_int2(cols[i], __float_as_int(vals[i]));
  }
}

__global__ void k_invdeg(const int* __restrict__ rowptr, float* __restrict__ invdeg, int n) {
  int i = blockIdx.x * blockDim.x + threadIdx.x;
  if (i < n) {
    int d = rowptr[i + 1] - rowptr[i];
    invdeg[i] = (d > 0) ? 1.0f / (float)d : 0.0f;
  }
}

// ---------------- region GEMM: cur[R0+i] = 0.8*cur[R0+i] + 0.2*(RW @ Rbuf)[i] ----------------

#define TI 16
#define TJ 32
__global__ void k_region(const float* __restrict__ RW, const float* __restrict__ Rb,
                         float* __restrict__ cur) {
  __shared__ float rw_s[TI][TJ];
  __shared__ float r_s[TJ][CHAN];
  int c = threadIdx.x;            // 0..127 channel
  int i0 = blockIdx.x * TI;
  float acc[TI];
#pragma unroll
  for (int r = 0; r < TI; ++r) acc[r] = 0.f;

  for (int j0 = 0; j0 < NREG; j0 += TJ) {
    for (int t = threadIdx.x; t < TI * TJ; t += 128) {
      int r = t / TJ, j = t % TJ;
      int gi = i0 + r, gj = j0 + j;
      rw_s[r][j] = (gi < NREG && gj < NREG) ? RW[gi * NREG + gj] : 0.f;
    }
#pragma unroll 4
    for (int j = 0; j < TJ; ++j) {
      int gj = j0 + j;
      r_s[j][c] = (gj < NREG) ? Rb[gj * CHAN + c] : 0.f;
    }
    __syncthreads();
#pragma unroll 8
    for (int j = 0; j < TJ; ++j) {
      float rv = r_s[j][c];
#pragma unroll
      for (int r = 0; r < TI; ++r) acc[r] += rw_s[r][j] * rv;
    }
    __syncthreads();
  }
#pragma unroll
  for (int r = 0; r < TI; ++r) {
    int gi = i0 + r;
    if (gi < NREG) {
      int idx = (REG0 + gi) * CHAN + c;
      cur[idx] = cur[idx] * 0.8f + acc[r] * 0.2f;
    }
  }
}

// ---------------- hot kernels: one wave per output row ----------------

__global__ void k_ent_agg(const float* __restrict__ cur, const int* __restrict__ rowptr,
                          const int* __restrict__ pk, const float* __restrict__ Wt,
                          const float* __restrict__ invdeg,
                          float* __restrict__ nxt, float* __restrict__ out_e) {
  int gid  = blockIdx.x * blockDim.x + threadIdx.x;
  int wave = gid >> 6;
  int lane = threadIdx.x & 63;
  if (wave >= N_ENT) return;
  int h = wave;
  int beg = rowptr[h], end = rowptr[h + 1];
  int c = lane * 2;
  float2 acc = make_float2(0.f, 0.f);
  for (int j = beg; j < end; ++j) {
    int p = pk[j];
    int t = p & 0x1FFFF;
    int r = p >> 17;
    float2 ev = *(const float2*)(cur + t * CHAN + c);
    float2 w  = *(const float2*)(Wt + r * CHAN + c);
    acc.x += ev.x * w.x;
    acc.y += ev.y * w.y;
  }
  float s = invdeg[h];
  acc.x *= s; acc.y *= s;
  float ss = acc.x * acc.x + acc.y * acc.y;
#pragma unroll
  for (int off = 32; off; off >>= 1) ss += __shfl_xor(ss, off, 64);
  float inv = 1.0f / fmaxf(sqrtf(ss), 1e-12f);
  acc.x *= inv; acc.y *= inv;
  *(float2*)(nxt + h * CHAN + c) = acc;
  float2 o = *(const float2*)(out_e + h * CHAN + c);
  o.x += acc.x; o.y += acc.y;
  *(float2*)(out_e + h * CHAN + c) = o;
}

__global__ void k_usr_agg(const float* __restrict__ cur, const int* __restrict__ rowptr,
                          const int2* __restrict__ pk, float* __restrict__ out_u) {
  int gid  = blockIdx.x * blockDim.x + threadIdx.x;
  int wave = gid >> 6;
  int lane = threadIdx.x & 63;
  if (wave >= N_USR) return;
  int u = wave;
  int beg = rowptr[u], end = rowptr[u + 1];
  int c = lane * 2;
  float2 acc = make_float2(0.f, 0.f);
  for (int j = beg; j < end; ++j) {
    int2 p = pk[j];
    int col = p.x;
    float v = __int_as_float(p.y);
    float2 ev = *(const float2*)(cur + col * CHAN + c);
    acc.x += v * ev.x;
    acc.y += v * ev.y;
  }
  float ss = acc.x * acc.x + acc.y * acc.y;
#pragma unroll
  for (int off = 32; off; off >>= 1) ss += __shfl_xor(ss, off, 64);
  float inv = 1.0f / fmaxf(sqrtf(ss), 1e-12f);
  acc.x *= inv; acc.y *= inv;
  float2 o = *(const float2*)(out_u + u * CHAN + c);
  o.x += acc.x; o.y += acc.y;
  *(float2*)(out_u + u * CHAN + c) = o;
}

// ---------------- launch ----------------

extern "C" void kernel_launch(void* const* d_in, const int* in_sizes, int n_in,
                              void* d_out, int out_size, void* d_ws, size_t ws_size,
                              hipStream_t stream) {
  const float* user_emb   = (const float*)d_in[0];
  const float* entity_emb = (const float*)d_in[1];
  const float* RW         = (const float*)d_in[2];
  const float* weight     = (const float*)d_in[3];
  const float* ivals      = (const float*)d_in[4];
  const int*   e_head     = (const int*)d_in[5];
  const int*   e_tail     = (const int*)d_in[6];
  const int*   e_type     = (const int*)d_in[7];
  const int*   i_rows     = (const int*)d_in[8];
  const int*   i_cols     = (const int*)d_in[9];

  float* out_e = (float*)d_out;                       // [N_ENT, 128]
  float* out_u = (float*)d_out + (size_t)N_ENT * CHAN; // [N_USR, 128]

  // workspace carve (256B aligned)
  char* p = (char*)d_ws;
  size_t off = 0;
  auto carve = [&](size_t bytes) -> void* {
    void* r = p + off;
    off += (bytes + 255) & ~(size_t)255;
    return r;
  };
  float* Ea       = (float*)carve((size_t)N_ENT * CHAN * 4);
  float* Eb       = (float*)carve((size_t)N_ENT * CHAN * 4);
  float* Rbuf     = (float*)carve((size_t)NREG * CHAN * 4);
  float* inv_deg  = (float*)carve((size_t)N_ENT * 4);
  int*   e_rowptr = (int*)carve((size_t)(N_ENT + 1) * 4);
  int*   e_cursor = (int*)carve((size_t)N_ENT * 4);
  int*   e_packed = (int*)carve((size_t)NEDGE * 4);
  int*   u_rowptr = (int*)carve((size_t)(N_USR + 1) * 4);
  int*   u_cursor = (int*)carve((size_t)N_USR * 4);
  int2*  u_packed = (int2*)carve((size_t)NNZI * 8);
  int*   partial  = (int*)carve((size_t)N_ENT * 4);
  int*   bsum     = (int*)carve(1024 * 4);
  int*   boff     = (int*)carve(1024 * 4);
  if (off > ws_size) return;  // workspace too small; bail (bench will flag)

  const int nbE = (N_ENT + SCAN_B - 1) / SCAN_B;  // 98
  const int nbU = (N_USR + SCAN_B - 1) / SCAN_B;  // 49

  // ---- CSR for edges (head -> packed tail|rel) ----
  hipMemsetAsync(e_cursor, 0, (size_t)N_ENT * 4, stream);
  k_hist<<<(NEDGE + 255) / 256, 256, 0, stream>>>(e_head, e_cursor, NEDGE);
  k_scan1<<<nbE, SCAN_B, 0, stream>>>(e_cursor, partial, bsum, N_ENT);
  k_scan2<<<1, SCAN_B, 0, stream>>>(bsum, boff, nbE);
  k_scan3<<<(N_ENT + 255) / 256, 256, 0, stream>>>(e_cursor, partial, boff, e_rowptr, N_ENT);
  k_scatter_e<<<(NEDGE + 255) / 256, 256, 0, stream>>>(e_head, e_tail, e_type, e_cursor,
                                                       e_packed, NEDGE);
  k_invdeg<<<(N_ENT + 255) / 256, 256, 0, stream>>>(e_rowptr, inv_deg, N_ENT);

  // ---- CSR for interactions (row -> {col, val}) ----
  hipMemsetAsync(u_cursor, 0, (size_t)N_USR * 4, stream);
  k_hist<<<(NNZI + 255) / 256, 256, 0, stream>>>(i_rows, u_cursor, NNZI);
  k_scan1<<<nbU, SCAN_B, 0, stream>>>(u_cursor, partial, bsum, N_USR);
  k_scan2<<<1, SCAN_B, 0, stream>>>(bsum, boff, nbU);
  k_scan3<<<(N_USR + 255) / 256, 256, 0, stream>>>(u_cursor, partial, boff, u_rowptr, N_USR);
  k_scatter_u<<<(NNZI + 255) / 256, 256, 0, stream>>>(i_rows, i_cols, ivals, u_cursor,
                                                      u_packed, NNZI);

  // ---- init: E_cur = entity_emb; out = [entity_emb, user_emb] ----
  hipMemcpyAsync(Ea, entity_emb, (size_t)N_ENT * CHAN * 4, hipMemcpyDeviceToDevice, stream);
  hipMemcpyAsync(out_e, entity_emb, (size_t)N_ENT * CHAN * 4, hipMemcpyDeviceToDevice, stream);
  hipMemcpyAsync(out_u, user_emb, (size_t)N_USR * CHAN * 4, hipMemcpyDeviceToDevice, stream);

  // ---- 3 hops ----
  for (int hop = 0; hop < 3; ++hop) {
    float* cur = (hop & 1) ? Eb : Ea;
    float* nxt = (hop & 1) ? Ea : Eb;
    hipMemcpyAsync(Rbuf, cur + (size_t)REG0 * CHAN, (size_t)NREG * CHAN * 4,
                   hipMemcpyDeviceToDevice, stream);
    k_region<<<(NREG + TI - 1) / TI, 128, 0, stream>>>(RW, Rbuf, cur);
    k_ent_agg<<<(N_ENT * 64) / 256, 256, 0, stream>>>(cur, e_rowptr, e_packed, weight,
                                                      inv_deg, nxt, out_e);
    k_usr_agg<<<(N_USR * 64) / 256, 256, 0, stream>>>(cur, u_rowptr, u_packed, out_u);
  }
}

// Round 2
// 2112.252 us; speedup vs baseline: 1.9906x; 1.9906x over previous
//
#include <hip/hip_runtime.h>
#include <stdint.h>

#define N_ENT 100000
#define N_USR 50000
#define NREG  2597
#define REG0  42033
#define CHAN  128
#define NEDGE 2000000
#define NNZI  1000000
#define SCAN_B 1024

// ---------------- CSR build ----------------

__global__ void k_hist(const int* __restrict__ idx, int* __restrict__ cnt, int n) {
  int i = blockIdx.x * blockDim.x + threadIdx.x;
  if (i < n) atomicAdd(&cnt[idx[i]], 1);
}

__global__ void k_scan1(const int* __restrict__ cnt, int* __restrict__ partial,
                        int* __restrict__ bsum, int n) {
  __shared__ int tmp[SCAN_B];
  int i = blockIdx.x * SCAN_B + threadIdx.x;
  int x = (i < n) ? cnt[i] : 0;
  tmp[threadIdx.x] = x;
  __syncthreads();
  for (int off = 1; off < SCAN_B; off <<= 1) {
    int y = (threadIdx.x >= off) ? tmp[threadIdx.x - off] : 0;
    __syncthreads();
    tmp[threadIdx.x] += y;
    __syncthreads();
  }
  if (i < n) partial[i] = tmp[threadIdx.x];
  if (threadIdx.x == SCAN_B - 1) bsum[blockIdx.x] = tmp[threadIdx.x];
}

__global__ void k_scan2(const int* __restrict__ bsum, int* __restrict__ boff, int nb) {
  __shared__ int tmp[SCAN_B];
  int x = (threadIdx.x < nb) ? bsum[threadIdx.x] : 0;
  tmp[threadIdx.x] = x;
  __syncthreads();
  for (int off = 1; off < SCAN_B; off <<= 1) {
    int y = (threadIdx.x >= off) ? tmp[threadIdx.x - off] : 0;
    __syncthreads();
    tmp[threadIdx.x] += y;
    __syncthreads();
  }
  if (threadIdx.x < nb) boff[threadIdx.x] = tmp[threadIdx.x] - x;  // exclusive
}

// cnt_cursor holds counts on entry, exclusive write-cursors on exit
__global__ void k_scan3(int* cnt_cursor, const int* __restrict__ partial,
                        const int* __restrict__ boff, int* __restrict__ rowptr, int n) {
  int i = blockIdx.x * blockDim.x + threadIdx.x;
  if (i < n) {
    int cv = cnt_cursor[i];
    int incl = partial[i] + boff[i / SCAN_B];
    rowptr[i + 1] = incl;
    cnt_cursor[i] = incl - cv;
    if (i == 0) rowptr[0] = 0;
  }
}

__global__ void k_scatter_e(const int* __restrict__ head, const int* __restrict__ tail,
                            const int* __restrict__ type, int* __restrict__ cursor,
                            int* __restrict__ pk, int n) {
  int i = blockIdx.x * blockDim.x + threadIdx.x;
  if (i < n) {
    int pos = atomicAdd(&cursor[head[i]], 1);
    pk[pos] = ((type[i] - 1) << 17) | tail[i];   // rel 5b | tail 17b
  }
}

__global__ void k_scatter_u(const int* __restrict__ rows, const int* __restrict__ cols,
                            const float* __restrict__ vals, int* __restrict__ cursor,
                            int2* __restrict__ pk, int n) {
  int i = blockIdx.x * blockDim.x + threadIdx.x;
  if (i < n) {
    int pos = atomicAdd(&cursor[rows[i]], 1);
    pk[pos] = make_int2(cols[i], __float_as_int(vals[i]));
  }
}

__global__ void k_invdeg(const int* __restrict__ rowptr, float* __restrict__ invdeg, int n) {
  int i = blockIdx.x * blockDim.x + threadIdx.x;
  if (i < n) {
    int d = rowptr[i + 1] - rowptr[i];
    invdeg[i] = (d > 0) ? 1.0f / (float)d : 0.0f;
  }
}

// ---------------- region GEMM (K-split, scalarized RW loads) ----------------
// Rtmp[i][c] += sum_{j in chunk} RW[i][j] * cur[REG0+j][c]
#define RTI 16                                  // rows per block
#define NROWT ((NREG + RTI - 1) / RTI)          // 163
#define NKC 8                                   // K chunks
#define KCH ((NREG + NKC - 1) / NKC)            // 325

__global__ __launch_bounds__(128) void k_region_gemm(const float* __restrict__ RW,
                                                     const float* __restrict__ cur,
                                                     float* __restrict__ Rtmp) {
  int c  = threadIdx.x;                 // channel 0..127
  int rt = blockIdx.x % NROWT;
  int kc = blockIdx.x / NROWT;
  int i0 = rt * RTI;
  int j_beg = kc * KCH;
  int j_end = j_beg + KCH;
  if (j_end > NREG) j_end = NREG;

  float acc[RTI];
#pragma unroll
  for (int r = 0; r < RTI; ++r) acc[r] = 0.f;

#pragma unroll 4
  for (int j = j_beg; j < j_end; ++j) {
    float rv = cur[(size_t)(REG0 + j) * CHAN + c];   // coalesced vector load
#pragma unroll
    for (int r = 0; r < RTI; ++r) {
      int gi = i0 + r;
      int gic = (gi < NREG) ? gi : (NREG - 1);       // clamp (uniform)
      float w = RW[(size_t)gic * NREG + j];          // block-uniform -> s_load
      acc[r] += w * rv;
    }
  }
#pragma unroll
  for (int r = 0; r < RTI; ++r) {
    int gi = i0 + r;
    if (gi < NREG) atomicAdd(&Rtmp[(size_t)gi * CHAN + c], acc[r]);
  }
}

__global__ void k_region_apply(float* __restrict__ cur, const float* __restrict__ Rtmp) {
  int i = blockIdx.x * blockDim.x + threadIdx.x;   // 0 .. NREG*CHAN-1
  if (i < NREG * CHAN) {
    size_t idx = (size_t)REG0 * CHAN + i;
    cur[idx] = cur[idx] * 0.8f + Rtmp[i] * 0.2f;
  }
}

// ---------------- hot kernels: one wave per output row ----------------

__global__ void k_ent_agg(const float* __restrict__ cur, const int* __restrict__ rowptr,
                          const int* __restrict__ pk, const float* __restrict__ Wt,
                          const float* __restrict__ invdeg,
                          float* __restrict__ nxt, float* __restrict__ out_e) {
  int gid  = blockIdx.x * blockDim.x + threadIdx.x;
  int wave = gid >> 6;
  int lane = threadIdx.x & 63;
  if (wave >= N_ENT) return;
  int h = wave;
  int beg = rowptr[h], end = rowptr[h + 1];
  int c = lane * 2;
  float2 acc = make_float2(0.f, 0.f);
  for (int j = beg; j < end; ++j) {
    int p = pk[j];
    int t = p & 0x1FFFF;
    int r = p >> 17;
    float2 ev = *(const float2*)(cur + t * CHAN + c);
    float2 w  = *(const float2*)(Wt + r * CHAN + c);
    acc.x += ev.x * w.x;
    acc.y += ev.y * w.y;
  }
  float s = invdeg[h];
  acc.x *= s; acc.y *= s;
  float ss = acc.x * acc.x + acc.y * acc.y;
#pragma unroll
  for (int off = 32; off; off >>= 1) ss += __shfl_xor(ss, off, 64);
  float inv = 1.0f / fmaxf(sqrtf(ss), 1e-12f);
  acc.x *= inv; acc.y *= inv;
  *(float2*)(nxt + h * CHAN + c) = acc;
  float2 o = *(const float2*)(out_e + h * CHAN + c);
  o.x += acc.x; o.y += acc.y;
  *(float2*)(out_e + h * CHAN + c) = o;
}

__global__ void k_usr_agg(const float* __restrict__ cur, const int* __restrict__ rowptr,
                          const int2* __restrict__ pk, float* __restrict__ out_u) {
  int gid  = blockIdx.x * blockDim.x + threadIdx.x;
  int wave = gid >> 6;
  int lane = threadIdx.x & 63;
  if (wave >= N_USR) return;
  int u = wave;
  int beg = rowptr[u], end = rowptr[u + 1];
  int c = lane * 2;
  float2 acc = make_float2(0.f, 0.f);
  for (int j = beg; j < end; ++j) {
    int2 p = pk[j];
    int col = p.x;
    float v = __int_as_float(p.y);
    float2 ev = *(const float2*)(cur + col * CHAN + c);
    acc.x += v * ev.x;
    acc.y += v * ev.y;
  }
  float ss = acc.x * acc.x + acc.y * acc.y;
#pragma unroll
  for (int off = 32; off; off >>= 1) ss += __shfl_xor(ss, off, 64);
  float inv = 1.0f / fmaxf(sqrtf(ss), 1e-12f);
  acc.x *= inv; acc.y *= inv;
  float2 o = *(const float2*)(out_u + u * CHAN + c);
  o.x += acc.x; o.y += acc.y;
  *(float2*)(out_u + u * CHAN + c) = o;
}

// ---------------- launch ----------------

extern "C" void kernel_launch(void* const* d_in, const int* in_sizes, int n_in,
                              void* d_out, int out_size, void* d_ws, size_t ws_size,
                              hipStream_t stream) {
  const float* user_emb   = (const float*)d_in[0];
  const float* entity_emb = (const float*)d_in[1];
  const float* RW         = (const float*)d_in[2];
  const float* weight     = (const float*)d_in[3];
  const float* ivals      = (const float*)d_in[4];
  const int*   e_head     = (const int*)d_in[5];
  const int*   e_tail     = (const int*)d_in[6];
  const int*   e_type     = (const int*)d_in[7];
  const int*   i_rows     = (const int*)d_in[8];
  const int*   i_cols     = (const int*)d_in[9];

  float* out_e = (float*)d_out;                        // [N_ENT, 128]
  float* out_u = (float*)d_out + (size_t)N_ENT * CHAN; // [N_USR, 128]

  // workspace carve (256B aligned)
  char* p = (char*)d_ws;
  size_t off = 0;
  auto carve = [&](size_t bytes) -> void* {
    void* r = p + off;
    off += (bytes + 255) & ~(size_t)255;
    return r;
  };
  float* Ea       = (float*)carve((size_t)N_ENT * CHAN * 4);
  float* Eb       = (float*)carve((size_t)N_ENT * CHAN * 4);
  float* Rtmp     = (float*)carve((size_t)NREG * CHAN * 4);
  float* inv_deg  = (float*)carve((size_t)N_ENT * 4);
  int*   e_rowptr = (int*)carve((size_t)(N_ENT + 1) * 4);
  int*   e_cursor = (int*)carve((size_t)N_ENT * 4);
  int*   e_packed = (int*)carve((size_t)NEDGE * 4);
  int*   u_rowptr = (int*)carve((size_t)(N_USR + 1) * 4);
  int*   u_cursor = (int*)carve((size_t)N_USR * 4);
  int2*  u_packed = (int2*)carve((size_t)NNZI * 8);
  int*   partial  = (int*)carve((size_t)N_ENT * 4);
  int*   bsum     = (int*)carve(1024 * 4);
  int*   boff     = (int*)carve(1024 * 4);
  if (off > ws_size) return;  // workspace too small; bail (bench will flag)

  const int nbE = (N_ENT + SCAN_B - 1) / SCAN_B;  // 98
  const int nbU = (N_USR + SCAN_B - 1) / SCAN_B;  // 49

  // ---- CSR for edges (head -> packed tail|rel) ----
  hipMemsetAsync(e_cursor, 0, (size_t)N_ENT * 4, stream);
  k_hist<<<(NEDGE + 255) / 256, 256, 0, stream>>>(e_head, e_cursor, NEDGE);
  k_scan1<<<nbE, SCAN_B, 0, stream>>>(e_cursor, partial, bsum, N_ENT);
  k_scan2<<<1, SCAN_B, 0, stream>>>(bsum, boff, nbE);
  k_scan3<<<(N_ENT + 255) / 256, 256, 0, stream>>>(e_cursor, partial, boff, e_rowptr, N_ENT);
  k_scatter_e<<<(NEDGE + 255) / 256, 256, 0, stream>>>(e_head, e_tail, e_type, e_cursor,
                                                       e_packed, NEDGE);
  k_invdeg<<<(N_ENT + 255) / 256, 256, 0, stream>>>(e_rowptr, inv_deg, N_ENT);

  // ---- CSR for interactions (row -> {col, val}) ----
  hipMemsetAsync(u_cursor, 0, (size_t)N_USR * 4, stream);
  k_hist<<<(NNZI + 255) / 256, 256, 0, stream>>>(i_rows, u_cursor, NNZI);
  k_scan1<<<nbU, SCAN_B, 0, stream>>>(u_cursor, partial, bsum, N_USR);
  k_scan2<<<1, SCAN_B, 0, stream>>>(bsum, boff, nbU);
  k_scan3<<<(N_USR + 255) / 256, 256, 0, stream>>>(u_cursor, partial, boff, u_rowptr, N_USR);
  k_scatter_u<<<(NNZI + 255) / 256, 256, 0, stream>>>(i_rows, i_cols, ivals, u_cursor,
                                                      u_packed, NNZI);

  // ---- init: E_cur = entity_emb; out = [entity_emb, user_emb] ----
  hipMemcpyAsync(Ea, entity_emb, (size_t)N_ENT * CHAN * 4, hipMemcpyDeviceToDevice, stream);
  hipMemcpyAsync(out_e, entity_emb, (size_t)N_ENT * CHAN * 4, hipMemcpyDeviceToDevice, stream);
  hipMemcpyAsync(out_u, user_emb, (size_t)N_USR * CHAN * 4, hipMemcpyDeviceToDevice, stream);

  // ---- 3 hops ----
  for (int hop = 0; hop < 3; ++hop) {
    float* cur = (hop & 1) ? Eb : Ea;
    float* nxt = (hop & 1) ? Ea : Eb;
    hipMemsetAsync(Rtmp, 0, (size_t)NREG * CHAN * 4, stream);
    k_region_gemm<<<NROWT * NKC, 128, 0, stream>>>(RW, cur, Rtmp);
    k_region_apply<<<(NREG * CHAN + 255) / 256, 256, 0, stream>>>(cur, Rtmp);
    k_ent_agg<<<(N_ENT * 64) / 256, 256, 0, stream>>>(cur, e_rowptr, e_packed, weight,
                                                      inv_deg, nxt, out_e);
    k_usr_agg<<<(N_USR * 64) / 256, 256, 0, stream>>>(cur, u_rowptr, u_packed, out_u);
  }
}

// Round 3
// 2057.732 us; speedup vs baseline: 2.0433x; 1.0265x over previous
//
#include <hip/hip_runtime.h>
#include <stdint.h>

#define N_ENT 100000
#define N_USR 50000
#define NREG  2597
#define REG0  42033
#define CHAN  128
#define NEDGE 2000000
#define NNZI  1000000
#define SCAN_B 1024

typedef unsigned int uint32;
typedef unsigned short ushort16;

__device__ __forceinline__ uint32 f2bf(float x) {
  uint32 b = __float_as_uint(x);
  b += 0x7FFFu + ((b >> 16) & 1u);   // round-to-nearest-even
  return b >> 16;
}
__device__ __forceinline__ float bf_lo(uint32 u) { return __uint_as_float(u << 16); }
__device__ __forceinline__ float bf_hi(uint32 u) { return __uint_as_float(u & 0xFFFF0000u); }

// ---------------- CSR build ----------------

__global__ void k_hist(const int* __restrict__ idx, int* __restrict__ cnt, int n) {
  int i = blockIdx.x * blockDim.x + threadIdx.x;
  if (i < n) atomicAdd(&cnt[idx[i]], 1);
}

__global__ void k_scan1(const int* __restrict__ cnt, int* __restrict__ partial,
                        int* __restrict__ bsum, int n) {
  __shared__ int tmp[SCAN_B];
  int i = blockIdx.x * SCAN_B + threadIdx.x;
  int x = (i < n) ? cnt[i] : 0;
  tmp[threadIdx.x] = x;
  __syncthreads();
  for (int off = 1; off < SCAN_B; off <<= 1) {
    int y = (threadIdx.x >= off) ? tmp[threadIdx.x - off] : 0;
    __syncthreads();
    tmp[threadIdx.x] += y;
    __syncthreads();
  }
  if (i < n) partial[i] = tmp[threadIdx.x];
  if (threadIdx.x == SCAN_B - 1) bsum[blockIdx.x] = tmp[threadIdx.x];
}

__global__ void k_scan2(const int* __restrict__ bsum, int* __restrict__ boff, int nb) {
  __shared__ int tmp[SCAN_B];
  int x = (threadIdx.x < nb) ? bsum[threadIdx.x] : 0;
  tmp[threadIdx.x] = x;
  __syncthreads();
  for (int off = 1; off < SCAN_B; off <<= 1) {
    int y = (threadIdx.x >= off) ? tmp[threadIdx.x - off] : 0;
    __syncthreads();
    tmp[threadIdx.x] += y;
    __syncthreads();
  }
  if (threadIdx.x < nb) boff[threadIdx.x] = tmp[threadIdx.x] - x;  // exclusive
}

__global__ void k_scan3(int* cnt_cursor, const int* __restrict__ partial,
                        const int* __restrict__ boff, int* __restrict__ rowptr, int n) {
  int i = blockIdx.x * blockDim.x + threadIdx.x;
  if (i < n) {
    int cv = cnt_cursor[i];
    int incl = partial[i] + boff[i / SCAN_B];
    rowptr[i + 1] = incl;
    cnt_cursor[i] = incl - cv;
    if (i == 0) rowptr[0] = 0;
  }
}

__global__ void k_scatter_e(const int* __restrict__ head, const int* __restrict__ tail,
                            const int* __restrict__ type, int* __restrict__ cursor,
                            int* __restrict__ pk, int n) {
  int i = blockIdx.x * blockDim.x + threadIdx.x;
  if (i < n) {
    int pos = atomicAdd(&cursor[head[i]], 1);
    pk[pos] = ((type[i] - 1) << 17) | tail[i];   // rel 5b | tail 17b
  }
}

__global__ void k_scatter_u(const int* __restrict__ rows, const int* __restrict__ cols,
                            const float* __restrict__ vals, int* __restrict__ cursor,
                            int2* __restrict__ pk, int n) {
  int i = blockIdx.x * blockDim.x + threadIdx.x;
  if (i < n) {
    int pos = atomicAdd(&cursor[rows[i]], 1);
    pk[pos] = make_int2(cols[i], __float_as_int(vals[i]));
  }
}

__global__ void k_invdeg(const int* __restrict__ rowptr, float* __restrict__ invdeg, int n) {
  int i = blockIdx.x * blockDim.x + threadIdx.x;
  if (i < n) {
    int d = rowptr[i + 1] - rowptr[i];
    invdeg[i] = (d > 0) ? 1.0f / (float)d : 0.0f;
  }
}

// ---------------- init cast: fp32 table -> bf16 table ----------------
__global__ void k_cast_bf16(const float* __restrict__ src, uint32* __restrict__ dst, int n4) {
  int i = blockIdx.x * blockDim.x + threadIdx.x;   // one per 4 floats
  if (i < n4) {
    float4 v = *(const float4*)(src + (size_t)i * 4);
    uint32 lo = f2bf(v.x) | (f2bf(v.y) << 16);
    uint32 hi = f2bf(v.z) | (f2bf(v.w) << 16);
    *(uint2*)(dst + (size_t)i * 2) = make_uint2(lo, hi);
  }
}

// ---------------- region GEMM on fp32 region buffer [NREG][CHAN] ----------------
#define RTI 16
#define NROWT ((NREG + RTI - 1) / RTI)          // 163
#define NKC 8
#define KCH ((NREG + NKC - 1) / NKC)            // 325

__global__ __launch_bounds__(128) void k_region_gemm(const float* __restrict__ RW,
                                                     const float* __restrict__ Rf,
                                                     float* __restrict__ Rtmp) {
  int c  = threadIdx.x;
  int rt = blockIdx.x % NROWT;
  int kc = blockIdx.x / NROWT;
  int i0 = rt * RTI;
  int j_beg = kc * KCH;
  int j_end = j_beg + KCH;
  if (j_end > NREG) j_end = NREG;

  float acc[RTI];
#pragma unroll
  for (int r = 0; r < RTI; ++r) acc[r] = 0.f;

#pragma unroll 4
  for (int j = j_beg; j < j_end; ++j) {
    float rv = Rf[(size_t)j * CHAN + c];
#pragma unroll
    for (int r = 0; r < RTI; ++r) {
      int gi = i0 + r;
      int gic = (gi < NREG) ? gi : (NREG - 1);
      float w = RW[(size_t)gic * NREG + j];
      acc[r] += w * rv;
    }
  }
#pragma unroll
  for (int r = 0; r < RTI; ++r) {
    int gi = i0 + r;
    if (gi < NREG) atomicAdd(&Rtmp[(size_t)gi * CHAN + c], acc[r]);
  }
}

// Rf = 0.8*Rf + 0.2*Rtmp ; mirror region rows into the bf16 gather table
__global__ void k_region_apply(float* __restrict__ Rf, const float* __restrict__ Rtmp,
                               ushort16* __restrict__ curB) {
  int i = blockIdx.x * blockDim.x + threadIdx.x;
  if (i < NREG * CHAN) {
    float v = Rf[i] * 0.8f + Rtmp[i] * 0.2f;
    Rf[i] = v;
    curB[(size_t)REG0 * CHAN + i] = (ushort16)f2bf(v);
  }
}

// ---------------- hot kernels: one wave per output row, bf16 gathers ----------------

__global__ void k_ent_agg(const ushort16* __restrict__ curB, const int* __restrict__ rowptr,
                          const int* __restrict__ pk, const float* __restrict__ Wt,
                          const float* __restrict__ invdeg,
                          uint32* __restrict__ nxtB, float* __restrict__ nxtRf,
                          float* __restrict__ out_e) {
  int gid  = blockIdx.x * blockDim.x + threadIdx.x;
  int wave = gid >> 6;
  int lane = threadIdx.x & 63;
  if (wave >= N_ENT) return;
  int h = wave;
  int beg = rowptr[h], end = rowptr[h + 1];
  int c = lane * 2;
  float2 acc = make_float2(0.f, 0.f);
  for (int j = beg; j < end; ++j) {
    int p = pk[j];
    int t = p & 0x1FFFF;
    int r = p >> 17;
    uint32 ev = *(const uint32*)(curB + (size_t)t * CHAN + c);
    float2 w  = *(const float2*)(Wt + (size_t)r * CHAN + c);
    acc.x += bf_lo(ev) * w.x;
    acc.y += bf_hi(ev) * w.y;
  }
  float s = invdeg[h];
  acc.x *= s; acc.y *= s;
  float ss = acc.x * acc.x + acc.y * acc.y;
#pragma unroll
  for (int off = 32; off; off >>= 1) ss += __shfl_xor(ss, off, 64);
  float inv = 1.0f / fmaxf(sqrtf(ss), 1e-12f);
  acc.x *= inv; acc.y *= inv;
  nxtB[(size_t)h * (CHAN / 2) + lane] = f2bf(acc.x) | (f2bf(acc.y) << 16);
  if (h >= REG0 && h < REG0 + NREG)
    *(float2*)(nxtRf + (size_t)(h - REG0) * CHAN + c) = acc;
  float2 o = *(const float2*)(out_e + (size_t)h * CHAN + c);
  o.x += acc.x; o.y += acc.y;
  *(float2*)(out_e + (size_t)h * CHAN + c) = o;
}

__global__ void k_usr_agg(const ushort16* __restrict__ curB, const int* __restrict__ rowptr,
                          const int2* __restrict__ pk, float* __restrict__ out_u) {
  int gid  = blockIdx.x * blockDim.x + threadIdx.x;
  int wave = gid >> 6;
  int lane = threadIdx.x & 63;
  if (wave >= N_USR) return;
  int u = wave;
  int beg = rowptr[u], end = rowptr[u + 1];
  int c = lane * 2;
  float2 acc = make_float2(0.f, 0.f);
  for (int j = beg; j < end; ++j) {
    int2 p = pk[j];
    int col = p.x;
    float v = __int_as_float(p.y);
    uint32 ev = *(const uint32*)(curB + (size_t)col * CHAN + c);
    acc.x += v * bf_lo(ev);
    acc.y += v * bf_hi(ev);
  }
  float ss = acc.x * acc.x + acc.y * acc.y;
#pragma unroll
  for (int off = 32; off; off >>= 1) ss += __shfl_xor(ss, off, 64);
  float inv = 1.0f / fmaxf(sqrtf(ss), 1e-12f);
  acc.x *= inv; acc.y *= inv;
  float2 o = *(const float2*)(out_u + (size_t)u * CHAN + c);
  o.x += acc.x; o.y += acc.y;
  *(float2*)(out_u + (size_t)u * CHAN + c) = o;
}

// ---------------- launch ----------------

extern "C" void kernel_launch(void* const* d_in, const int* in_sizes, int n_in,
                              void* d_out, int out_size, void* d_ws, size_t ws_size,
                              hipStream_t stream) {
  const float* user_emb   = (const float*)d_in[0];
  const float* entity_emb = (const float*)d_in[1];
  const float* RW         = (const float*)d_in[2];
  const float* weight     = (const float*)d_in[3];
  const float* ivals      = (const float*)d_in[4];
  const int*   e_head     = (const int*)d_in[5];
  const int*   e_tail     = (const int*)d_in[6];
  const int*   e_type     = (const int*)d_in[7];
  const int*   i_rows     = (const int*)d_in[8];
  const int*   i_cols     = (const int*)d_in[9];

  float* out_e = (float*)d_out;                        // [N_ENT, 128]
  float* out_u = (float*)d_out + (size_t)N_ENT * CHAN; // [N_USR, 128]

  char* p = (char*)d_ws;
  size_t off = 0;
  auto carve = [&](size_t bytes) -> void* {
    void* r = p + off;
    off += (bytes + 255) & ~(size_t)255;
    return r;
  };
  ushort16* B16a   = (ushort16*)carve((size_t)N_ENT * CHAN * 2);
  ushort16* B16b   = (ushort16*)carve((size_t)N_ENT * CHAN * 2);
  float* Rfa       = (float*)carve((size_t)NREG * CHAN * 4);
  float* Rfb       = (float*)carve((size_t)NREG * CHAN * 4);
  float* Rtmp      = (float*)carve((size_t)NREG * CHAN * 4);
  float* inv_deg   = (float*)carve((size_t)N_ENT * 4);
  int*   e_rowptr  = (int*)carve((size_t)(N_ENT + 1) * 4);
  int*   e_cursor  = (int*)carve((size_t)N_ENT * 4);
  int*   e_packed  = (int*)carve((size_t)NEDGE * 4);
  int*   u_rowptr  = (int*)carve((size_t)(N_USR + 1) * 4);
  int*   u_cursor  = (int*)carve((size_t)N_USR * 4);
  int2*  u_packed  = (int2*)carve((size_t)NNZI * 8);
  int*   partial   = (int*)carve((size_t)N_ENT * 4);
  int*   bsum      = (int*)carve(1024 * 4);
  int*   boff      = (int*)carve(1024 * 4);
  if (off > ws_size) return;

  const int nbE = (N_ENT + SCAN_B - 1) / SCAN_B;
  const int nbU = (N_USR + SCAN_B - 1) / SCAN_B;

  // ---- CSR for edges ----
  hipMemsetAsync(e_cursor, 0, (size_t)N_ENT * 4, stream);
  k_hist<<<(NEDGE + 255) / 256, 256, 0, stream>>>(e_head, e_cursor, NEDGE);
  k_scan1<<<nbE, SCAN_B, 0, stream>>>(e_cursor, partial, bsum, N_ENT);
  k_scan2<<<1, SCAN_B, 0, stream>>>(bsum, boff, nbE);
  k_scan3<<<(N_ENT + 255) / 256, 256, 0, stream>>>(e_cursor, partial, boff, e_rowptr, N_ENT);
  k_scatter_e<<<(NEDGE + 255) / 256, 256, 0, stream>>>(e_head, e_tail, e_type, e_cursor,
                                                       e_packed, NEDGE);
  k_invdeg<<<(N_ENT + 255) / 256, 256, 0, stream>>>(e_rowptr, inv_deg, N_ENT);

  // ---- CSR for interactions ----
  hipMemsetAsync(u_cursor, 0, (size_t)N_USR * 4, stream);
  k_hist<<<(NNZI + 255) / 256, 256, 0, stream>>>(i_rows, u_cursor, NNZI);
  k_scan1<<<nbU, SCAN_B, 0, stream>>>(u_cursor, partial, bsum, N_USR);
  k_scan2<<<1, SCAN_B, 0, stream>>>(bsum, boff, nbU);
  k_scan3<<<(N_USR + 255) / 256, 256, 0, stream>>>(u_cursor, partial, boff, u_rowptr, N_USR);
  k_scatter_u<<<(NNZI + 255) / 256, 256, 0, stream>>>(i_rows, i_cols, ivals, u_cursor,
                                                      u_packed, NNZI);

  // ---- init ----
  k_cast_bf16<<<(N_ENT * CHAN / 4 + 255) / 256, 256, 0, stream>>>(
      entity_emb, (uint32*)B16a, N_ENT * CHAN / 4);
  hipMemcpyAsync(Rfa, entity_emb + (size_t)REG0 * CHAN, (size_t)NREG * CHAN * 4,
                 hipMemcpyDeviceToDevice, stream);
  hipMemcpyAsync(out_e, entity_emb, (size_t)N_ENT * CHAN * 4, hipMemcpyDeviceToDevice, stream);
  hipMemcpyAsync(out_u, user_emb, (size_t)N_USR * CHAN * 4, hipMemcpyDeviceToDevice, stream);

  // ---- 3 hops ----
  for (int hop = 0; hop < 3; ++hop) {
    ushort16* curB = (hop & 1) ? B16b : B16a;
    ushort16* nxtB = (hop & 1) ? B16a : B16b;
    float*    curR = (hop & 1) ? Rfb : Rfa;
    float*    nxtR = (hop & 1) ? Rfa : Rfb;
    hipMemsetAsync(Rtmp, 0, (size_t)NREG * CHAN * 4, stream);
    k_region_gemm<<<NROWT * NKC, 128, 0, stream>>>(RW, curR, Rtmp);
    k_region_apply<<<(NREG * CHAN + 255) / 256, 256, 0, stream>>>(curR, Rtmp, curB);
    k_ent_agg<<<(N_ENT * 64) / 256, 256, 0, stream>>>(curB, e_rowptr, e_packed, weight,
                                                      inv_deg, (uint32*)nxtB, nxtR, out_e);
    k_usr_agg<<<(N_USR * 64) / 256, 256, 0, stream>>>(curB, u_rowptr, u_packed, out_u);
  }
}

// Round 4
// 1760.472 us; speedup vs baseline: 2.3883x; 1.1689x over previous
//
#include <hip/hip_runtime.h>
#include <stdint.h>

#define N_ENT 100000
#define N_USR 50000
#define NREG  2597
#define REG0  42033
#define CHAN  128
#define NEDGE 2000000
#define NNZI  1000000
#define SCAN_B 1024
#define RWPITCH 2600            // padded K pitch (multiple of 8 -> 32B aligned rows)

typedef unsigned int uint32;
typedef unsigned short ushort16;
typedef float float8 __attribute__((ext_vector_type(8)));

__device__ __forceinline__ uint32 f2bf(float x) {
  uint32 b = __float_as_uint(x);
  b += 0x7FFFu + ((b >> 16) & 1u);   // round-to-nearest-even
  return b >> 16;
}
__device__ __forceinline__ float bf_lo(uint32 u) { return __uint_as_float(u << 16); }
__device__ __forceinline__ float bf_hi(uint32 u) { return __uint_as_float(u & 0xFFFF0000u); }

// ---------------- CSR build ----------------

__global__ void k_hist(const int* __restrict__ idx, int* __restrict__ cnt, int n) {
  int i = blockIdx.x * blockDim.x + threadIdx.x;
  if (i < n) atomicAdd(&cnt[idx[i]], 1);
}

__global__ void k_scan1(const int* __restrict__ cnt, int* __restrict__ partial,
                        int* __restrict__ bsum, int n) {
  __shared__ int tmp[SCAN_B];
  int i = blockIdx.x * SCAN_B + threadIdx.x;
  int x = (i < n) ? cnt[i] : 0;
  tmp[threadIdx.x] = x;
  __syncthreads();
  for (int off = 1; off < SCAN_B; off <<= 1) {
    int y = (threadIdx.x >= off) ? tmp[threadIdx.x - off] : 0;
    __syncthreads();
    tmp[threadIdx.x] += y;
    __syncthreads();
  }
  if (i < n) partial[i] = tmp[threadIdx.x];
  if (threadIdx.x == SCAN_B - 1) bsum[blockIdx.x] = tmp[threadIdx.x];
}

__global__ void k_scan2(const int* __restrict__ bsum, int* __restrict__ boff, int nb) {
  __shared__ int tmp[SCAN_B];
  int x = (threadIdx.x < nb) ? bsum[threadIdx.x] : 0;
  tmp[threadIdx.x] = x;
  __syncthreads();
  for (int off = 1; off < SCAN_B; off <<= 1) {
    int y = (threadIdx.x >= off) ? tmp[threadIdx.x - off] : 0;
    __syncthreads();
    tmp[threadIdx.x] += y;
    __syncthreads();
  }
  if (threadIdx.x < nb) boff[threadIdx.x] = tmp[threadIdx.x] - x;  // exclusive
}

__global__ void k_scan3(int* cnt_cursor, const int* __restrict__ partial,
                        const int* __restrict__ boff, int* __restrict__ rowptr, int n) {
  int i = blockIdx.x * blockDim.x + threadIdx.x;
  if (i < n) {
    int cv = cnt_cursor[i];
    int incl = partial[i] + boff[i / SCAN_B];
    rowptr[i + 1] = incl;
    cnt_cursor[i] = incl - cv;
    if (i == 0) rowptr[0] = 0;
  }
}

__global__ void k_scatter_e(const int* __restrict__ head, const int* __restrict__ tail,
                            const int* __restrict__ type, int* __restrict__ cursor,
                            int* __restrict__ pk, int n) {
  int i = blockIdx.x * blockDim.x + threadIdx.x;
  if (i < n) {
    int pos = atomicAdd(&cursor[head[i]], 1);
    pk[pos] = ((type[i] - 1) << 17) | tail[i];   // rel 5b | tail 17b
  }
}

__global__ void k_scatter_u(const int* __restrict__ rows, const int* __restrict__ cols,
                            const float* __restrict__ vals, int* __restrict__ cursor,
                            int2* __restrict__ pk, int n) {
  int i = blockIdx.x * blockDim.x + threadIdx.x;
  if (i < n) {
    int pos = atomicAdd(&cursor[rows[i]], 1);
    pk[pos] = make_int2(cols[i], __float_as_int(vals[i]));
  }
}

__global__ void k_invdeg(const int* __restrict__ rowptr, float* __restrict__ invdeg, int n) {
  int i = blockIdx.x * blockDim.x + threadIdx.x;
  if (i < n) {
    int d = rowptr[i + 1] - rowptr[i];
    invdeg[i] = (d > 0) ? 1.0f / (float)d : 0.0f;
  }
}

// ---------------- init cast: fp32 table -> bf16 table ----------------
__global__ void k_cast_bf16(const float* __restrict__ src, uint32* __restrict__ dst, int n4) {
  int i = blockIdx.x * blockDim.x + threadIdx.x;
  if (i < n4) {
    float4 v = *(const float4*)(src + (size_t)i * 4);
    uint32 lo = f2bf(v.x) | (f2bf(v.y) << 16);
    uint32 hi = f2bf(v.z) | (f2bf(v.w) << 16);
    *(uint2*)(dst + (size_t)i * 2) = make_uint2(lo, hi);
  }
}

// ---------------- pad RW into aligned-pitch copy ----------------
__global__ void k_pad_rw(const float* __restrict__ src, float* __restrict__ dst) {
  int i = blockIdx.x * blockDim.x + threadIdx.x;   // over NREG * (RWPITCH/4)
  const int C4 = RWPITCH / 4;                       // 650
  if (i >= NREG * C4) return;
  int r = i / C4, c = (i % C4) * 4;
  float4 v;
  v.x = (c + 0 < NREG) ? src[(size_t)r * NREG + c + 0] : 0.f;
  v.y = (c + 1 < NREG) ? src[(size_t)r * NREG + c + 1] : 0.f;
  v.z = (c + 2 < NREG) ? src[(size_t)r * NREG + c + 2] : 0.f;
  v.w = (c + 3 < NREG) ? src[(size_t)r * NREG + c + 3] : 0.f;
  *(float4*)(dst + (size_t)r * RWPITCH + c) = v;
}

// ---------------- region GEMM (K-split, s_load_dwordx8 RW, fp32 VALU) ----------------
#define RTI 16
#define NROWT ((NREG + RTI - 1) / RTI)          // 163
#define NKC 8
#define NGRP (RWPITCH / 8)                      // 325 groups of 8 K
#define GPC  ((NGRP + NKC - 1) / NKC)           // 41 groups per chunk

__global__ __launch_bounds__(128) void k_region_gemm(const float* __restrict__ RWp,
                                                     const float* __restrict__ Rf,
                                                     float* __restrict__ Rtmp) {
  int c  = threadIdx.x;                 // channel 0..127
  int rt = blockIdx.x % NROWT;
  int kc = blockIdx.x / NROWT;
  int i0 = rt * RTI;
  int g_beg = kc * GPC;
  int g_end = g_beg + GPC;
  if (g_end > NGRP) g_end = NGRP;

  float acc[RTI];
#pragma unroll
  for (int r = 0; r < RTI; ++r) acc[r] = 0.f;

  for (int g = g_beg; g < g_end; ++g) {
    int j = g * 8;
    float xv[8];
#pragma unroll
    for (int jj = 0; jj < 8; ++jj)
      xv[jj] = Rf[(size_t)(j + jj) * CHAN + c];   // coalesced; pad rows are 0
#pragma unroll
    for (int r = 0; r < RTI; ++r) {
      int gi = i0 + r;
      int gic = (gi < NREG) ? gi : (NREG - 1);    // uniform clamp
      float8 w = *(const float8*)(RWp + (size_t)gic * RWPITCH + j);  // s_load_dwordx8
#pragma unroll
      for (int jj = 0; jj < 8; ++jj) acc[r] += w[jj] * xv[jj];
    }
  }
#pragma unroll
  for (int r = 0; r < RTI; ++r) {
    int gi = i0 + r;
    if (gi < NREG) atomicAdd(&Rtmp[(size_t)gi * CHAN + c], acc[r]);
  }
}

// Rf = 0.8*Rf + 0.2*Rtmp ; mirror region rows into the bf16 gather table
__global__ void k_region_apply(float* __restrict__ Rf, const float* __restrict__ Rtmp,
                               ushort16* __restrict__ curB) {
  int i = blockIdx.x * blockDim.x + threadIdx.x;
  if (i < NREG * CHAN) {
    float v = Rf[i] * 0.8f + Rtmp[i] * 0.2f;
    Rf[i] = v;
    curB[(size_t)REG0 * CHAN + i] = (ushort16)f2bf(v);
  }
}

// ---------------- hot kernels: one wave per output row, bf16 gathers ----------------

__global__ void k_ent_agg(const ushort16* __restrict__ curB, const int* __restrict__ rowptr,
                          const int* __restrict__ pk, const float* __restrict__ Wt,
                          const float* __restrict__ invdeg,
                          uint32* __restrict__ nxtB, float* __restrict__ nxtRf,
                          float* __restrict__ out_e) {
  int gid  = blockIdx.x * blockDim.x + threadIdx.x;
  int wave = gid >> 6;
  int lane = threadIdx.x & 63;
  if (wave >= N_ENT) return;
  int h = wave;
  int beg = rowptr[h], end = rowptr[h + 1];
  int c = lane * 2;
  float2 acc = make_float2(0.f, 0.f);
  for (int j = beg; j < end; ++j) {
    int p = pk[j];
    int t = p & 0x1FFFF;
    int r = p >> 17;
    uint32 ev = *(const uint32*)(curB + (size_t)t * CHAN + c);
    float2 w  = *(const float2*)(Wt + (size_t)r * CHAN + c);
    acc.x += bf_lo(ev) * w.x;
    acc.y += bf_hi(ev) * w.y;
  }
  float s = invdeg[h];
  acc.x *= s; acc.y *= s;
  float ss = acc.x * acc.x + acc.y * acc.y;
#pragma unroll
  for (int off = 32; off; off >>= 1) ss += __shfl_xor(ss, off, 64);
  float inv = 1.0f / fmaxf(sqrtf(ss), 1e-12f);
  acc.x *= inv; acc.y *= inv;
  nxtB[(size_t)h * (CHAN / 2) + lane] = f2bf(acc.x) | (f2bf(acc.y) << 16);
  if (h >= REG0 && h < REG0 + NREG)
    *(float2*)(nxtRf + (size_t)(h - REG0) * CHAN + c) = acc;
  float2 o = *(const float2*)(out_e + (size_t)h * CHAN + c);
  o.x += acc.x; o.y += acc.y;
  *(float2*)(out_e + (size_t)h * CHAN + c) = o;
}

__global__ void k_usr_agg(const ushort16* __restrict__ curB, const int* __restrict__ rowptr,
                          const int2* __restrict__ pk, float* __restrict__ out_u) {
  int gid  = blockIdx.x * blockDim.x + threadIdx.x;
  int wave = gid >> 6;
  int lane = threadIdx.x & 63;
  if (wave >= N_USR) return;
  int u = wave;
  int beg = rowptr[u], end = rowptr[u + 1];
  int c = lane * 2;
  float2 acc = make_float2(0.f, 0.f);
  for (int j = beg; j < end; ++j) {
    int2 p = pk[j];
    int col = p.x;
    float v = __int_as_float(p.y);
    uint32 ev = *(const uint32*)(curB + (size_t)col * CHAN + c);
    acc.x += v * bf_lo(ev);
    acc.y += v * bf_hi(ev);
  }
  float ss = acc.x * acc.x + acc.y * acc.y;
#pragma unroll
  for (int off = 32; off; off >>= 1) ss += __shfl_xor(ss, off, 64);
  float inv = 1.0f / fmaxf(sqrtf(ss), 1e-12f);
  acc.x *= inv; acc.y *= inv;
  float2 o = *(const float2*)(out_u + (size_t)u * CHAN + c);
  o.x += acc.x; o.y += acc.y;
  *(float2*)(out_u + (size_t)u * CHAN + c) = o;
}

// ---------------- launch ----------------

extern "C" void kernel_launch(void* const* d_in, const int* in_sizes, int n_in,
                              void* d_out, int out_size, void* d_ws, size_t ws_size,
                              hipStream_t stream) {
  const float* user_emb   = (const float*)d_in[0];
  const float* entity_emb = (const float*)d_in[1];
  const float* RW         = (const float*)d_in[2];
  const float* weight     = (const float*)d_in[3];
  const float* ivals      = (const float*)d_in[4];
  const int*   e_head     = (const int*)d_in[5];
  const int*   e_tail     = (const int*)d_in[6];
  const int*   e_type     = (const int*)d_in[7];
  const int*   i_rows     = (const int*)d_in[8];
  const int*   i_cols     = (const int*)d_in[9];

  float* out_e = (float*)d_out;                        // [N_ENT, 128]
  float* out_u = (float*)d_out + (size_t)N_ENT * CHAN; // [N_USR, 128]

  char* p = (char*)d_ws;
  size_t off = 0;
  auto carve = [&](size_t bytes) -> void* {
    void* r = p + off;
    off += (bytes + 255) & ~(size_t)255;
    return r;
  };
  ushort16* B16a   = (ushort16*)carve((size_t)N_ENT * CHAN * 2);
  ushort16* B16b   = (ushort16*)carve((size_t)N_ENT * CHAN * 2);
  float* RWp       = (float*)carve((size_t)NREG * RWPITCH * 4);
  float* Rfa       = (float*)carve((size_t)RWPITCH * CHAN * 4);   // 2600 rows (pad zeroed)
  float* Rfb       = (float*)carve((size_t)RWPITCH * CHAN * 4);
  float* Rtmp      = (float*)carve((size_t)NREG * CHAN * 4);
  float* inv_deg   = (float*)carve((size_t)N_ENT * 4);
  int*   e_rowptr  = (int*)carve((size_t)(N_ENT + 1) * 4);
  int*   e_cursor  = (int*)carve((size_t)N_ENT * 4);
  int*   e_packed  = (int*)carve((size_t)NEDGE * 4);
  int*   u_rowptr  = (int*)carve((size_t)(N_USR + 1) * 4);
  int*   u_cursor  = (int*)carve((size_t)N_USR * 4);
  int2*  u_packed  = (int2*)carve((size_t)NNZI * 8);
  int*   partial   = (int*)carve((size_t)N_ENT * 4);
  int*   bsum      = (int*)carve(1024 * 4);
  int*   boff      = (int*)carve(1024 * 4);
  if (off > ws_size) return;

  const int nbE = (N_ENT + SCAN_B - 1) / SCAN_B;
  const int nbU = (N_USR + SCAN_B - 1) / SCAN_B;

  // ---- CSR for edges ----
  hipMemsetAsync(e_cursor, 0, (size_t)N_ENT * 4, stream);
  k_hist<<<(NEDGE + 255) / 256, 256, 0, stream>>>(e_head, e_cursor, NEDGE);
  k_scan1<<<nbE, SCAN_B, 0, stream>>>(e_cursor, partial, bsum, N_ENT);
  k_scan2<<<1, SCAN_B, 0, stream>>>(bsum, boff, nbE);
  k_scan3<<<(N_ENT + 255) / 256, 256, 0, stream>>>(e_cursor, partial, boff, e_rowptr, N_ENT);
  k_scatter_e<<<(NEDGE + 255) / 256, 256, 0, stream>>>(e_head, e_tail, e_type, e_cursor,
                                                       e_packed, NEDGE);
  k_invdeg<<<(N_ENT + 255) / 256, 256, 0, stream>>>(e_rowptr, inv_deg, N_ENT);

  // ---- CSR for interactions ----
  hipMemsetAsync(u_cursor, 0, (size_t)N_USR * 4, stream);
  k_hist<<<(NNZI + 255) / 256, 256, 0, stream>>>(i_rows, u_cursor, NNZI);
  k_scan1<<<nbU, SCAN_B, 0, stream>>>(u_cursor, partial, bsum, N_USR);
  k_scan2<<<1, SCAN_B, 0, stream>>>(bsum, boff, nbU);
  k_scan3<<<(N_USR + 255) / 256, 256, 0, stream>>>(u_cursor, partial, boff, u_rowptr, N_USR);
  k_scatter_u<<<(NNZI + 255) / 256, 256, 0, stream>>>(i_rows, i_cols, ivals, u_cursor,
                                                      u_packed, NNZI);

  // ---- init ----
  k_pad_rw<<<(NREG * (RWPITCH / 4) + 255) / 256, 256, 0, stream>>>(RW, RWp);
  k_cast_bf16<<<(N_ENT * CHAN / 4 + 255) / 256, 256, 0, stream>>>(
      entity_emb, (uint32*)B16a, N_ENT * CHAN / 4);
  hipMemsetAsync(Rfa, 0, (size_t)RWPITCH * CHAN * 4, stream);
  hipMemsetAsync(Rfb, 0, (size_t)RWPITCH * CHAN * 4, stream);
  hipMemcpyAsync(Rfa, entity_emb + (size_t)REG0 * CHAN, (size_t)NREG * CHAN * 4,
                 hipMemcpyDeviceToDevice, stream);
  hipMemcpyAsync(out_e, entity_emb, (size_t)N_ENT * CHAN * 4, hipMemcpyDeviceToDevice, stream);
  hipMemcpyAsync(out_u, user_emb, (size_t)N_USR * CHAN * 4, hipMemcpyDeviceToDevice, stream);

  // ---- 3 hops ----
  for (int hop = 0; hop < 3; ++hop) {
    ushort16* curB = (hop & 1) ? B16b : B16a;
    ushort16* nxtB = (hop & 1) ? B16a : B16b;
    float*    curR = (hop & 1) ? Rfb : Rfa;
    float*    nxtR = (hop & 1) ? Rfa : Rfb;
    hipMemsetAsync(Rtmp, 0, (size_t)NREG * CHAN * 4, stream);
    k_region_gemm<<<NROWT * NKC, 128, 0, stream>>>(RWp, curR, Rtmp);
    k_region_apply<<<(NREG * CHAN + 255) / 256, 256, 0, stream>>>(curR, Rtmp, curB);
    k_ent_agg<<<(N_ENT * 64) / 256, 256, 0, stream>>>(curB, e_rowptr, e_packed, weight,
                                                      inv_deg, (uint32*)nxtB, nxtR, out_e);
    k_usr_agg<<<(N_USR * 64) / 256, 256, 0, stream>>>(curB, u_rowptr, u_packed, out_u);
  }
}